// Round 4
// baseline (229.659 us; speedup 1.0000x reference)
//
#include <hip/hip_runtime.h>
#include <math.h>

namespace {
constexpr int B    = 4;
constexpr int N    = 8192;
constexpr int P    = 2048;
constexpr int C    = 128;
constexpr int COUT = 256;
constexpr int NS   = 32;
constexpr int BP   = B * P;     // 8192
constexpr int BPB  = 4;         // bp per group
constexpr int GRP  = 4;         // groups per block
constexpr int NBLK = BP / (BPB * GRP); // 512 blocks (2/CU)

// ---- workspace layout (bytes, all 256-aligned) ----
constexpr size_t OFF_FEATT = 0;                          // B*N*C bf16    = 8388608
constexpr size_t OFF_WSWZ  = 8388608;                    // 40960 bf16    = 81920
constexpr size_t OFF_NXD   = 8470528;                    // 8192*3 f64    = 196608
constexpr size_t OFF_NXF   = 8667136;                    // 8192*3 f32    = 98304
constexpr size_t OFF_IDX   = 8765440;                    // 8192*32 i32   = 1048576
constexpr size_t OFF_YMAX  = 9814016;                    // 8192*256 f32  = 8388608
constexpr size_t OFF_PART  = 18202624;                   // 512*512 f32   = 1048576
constexpr size_t OFF_P2    = 19251200;                   // 128*512 f32   = 262144
constexpr size_t OFF_AB    = 19513344;                   // 512 f32       = 2048
constexpr size_t WS_NEED   = 19515392;                   // ~18.6 MB
} // namespace

typedef short bf16x8 __attribute__((ext_vector_type(8)));
typedef float f32x4  __attribute__((ext_vector_type(4)));

typedef const __attribute__((address_space(1))) void gas_void;
typedef __attribute__((address_space(3))) void las_void;
#define GLOBAL_LOAD_LDS16(gp, lp) \
    __builtin_amdgcn_global_load_lds((gas_void*)(gp), (las_void*)(lp), 16, 0, 0)

__device__ inline unsigned short f2bf(float f) {
    unsigned u = __float_as_uint(f);
    unsigned r = u + 0x7fffu + ((u >> 16) & 1u);
    return (unsigned short)(r >> 16);
}

// ---------------- K0a: transpose features (B,C,N) f32 -> (B,N,C) bf16 ----------------
__global__ __launch_bounds__(256) void k_transpose(const float* __restrict__ feat,
                                                   unsigned short* __restrict__ featT) {
    __shared__ float tile[64][33];
    int tx = threadIdx.x, ty = threadIdx.y;        // 32 x 8
    int n0 = blockIdx.x * 32, c0 = blockIdx.y * 64, b = blockIdx.z;
    const float* src = feat + ((size_t)b * C + c0) * N + n0;
#pragma unroll
    for (int j = 0; j < 8; j++) tile[ty + 8 * j][tx] = src[(size_t)(ty + 8 * j) * N + tx];
    __syncthreads();
#pragma unroll
    for (int j = 0; j < 4; j++) {
        int n = ty + 8 * j;
        unsigned v = (unsigned)f2bf(tile[2 * tx][n]) | ((unsigned)f2bf(tile[2 * tx + 1][n]) << 16);
        *(unsigned*)&featT[((size_t)b * N + n0 + n) * C + c0 + 2 * tx] = v;
    }
}

// ---------------- K0b: swizzle w_mlp into MFMA fragment order (bf16) ----------------
// wswz[rt(16)][ks(5)][lane(64)][j(8)]; element = W[rt*16+(lane&15)][k'] with
// k' = ks*32+(lane>>4)*8+j; k-map: 0..127 -> w col 3+k' (feats); 128..130 -> w col
// 0..2 (xyz); else 0. Serves as A-frag (m=cout) in R2/R3 and equally as B-frag
// (n=cout) now — A and B index maps are identical.
__global__ __launch_bounds__(256) void k_wswz(const float* __restrict__ w,
                                              unsigned short* __restrict__ wswz) {
    int i = blockIdx.x * 256 + threadIdx.x;        // < 40960
    int j = i & 7;
    int lane = (i >> 3) & 63;
    int rest = i >> 9;                             // 0..79
    int ks = rest % 5, rt = rest / 5;
    int cout = rt * 16 + (lane & 15);
    int k = ks * 32 + (lane >> 4) * 8 + j;
    float v = 0.f;
    if (k < 128) v = w[cout * 131 + 3 + k];
    else if (k < 131) v = w[cout * 131 + (k - 128)];
    wswz[i] = f2bf(v);
}

// ---------------- K1: shift conv + BN(train) + ReLU, fp64 to match np ref ----------------
__global__ __launch_bounds__(1024) void k_shift(const float* __restrict__ ffps,
                                                const float* __restrict__ wsh,
                                                const float* __restrict__ gam,
                                                const float* __restrict__ bet,
                                                double* __restrict__ nxd,
                                                float* __restrict__ nxf) {
#pragma clang fp contract(off)
    __shared__ double red[6][1024];
    __shared__ double par[6];
    int t = threadIdx.x;
    double w[9];
#pragma unroll
    for (int i = 0; i < 9; i++) w[i] = (double)wsh[i];
    double x[8][3];
    double s[3] = {0, 0, 0}, sq[3] = {0, 0, 0};
#pragma unroll
    for (int i = 0; i < 8; i++) {
        int p = t + 1024 * i;
        double f0 = (double)ffps[p * 3 + 0];
        double f1 = (double)ffps[p * 3 + 1];
        double f2 = (double)ffps[p * 3 + 2];
#pragma unroll
        for (int o = 0; o < 3; o++) {
            double xo = (w[o * 3 + 0] * f0 + w[o * 3 + 1] * f1) + w[o * 3 + 2] * f2;
            x[i][o] = xo;
            s[o] += xo;
            sq[o] += xo * xo;
        }
    }
#pragma unroll
    for (int o = 0; o < 3; o++) { red[o][t] = s[o]; red[3 + o][t] = sq[o]; }
    for (int off = 512; off > 0; off >>= 1) {
        __syncthreads();
        if (t < off) {
#pragma unroll
            for (int j = 0; j < 6; j++) red[j][t] += red[j][t + off];
        }
    }
    __syncthreads();
    if (t == 0) {
#pragma unroll
        for (int o = 0; o < 3; o++) {
            double m = red[o][0] / (double)BP;
            double v = red[3 + o][0] / (double)BP - m * m;
            par[o] = m;
            par[3 + o] = 1.0 / sqrt(v + 1e-5);
        }
    }
    __syncthreads();
    double gv[3] = {(double)gam[0], (double)gam[1], (double)gam[2]};
    double bv[3] = {(double)bet[0], (double)bet[1], (double)bet[2]};
#pragma unroll
    for (int i = 0; i < 8; i++) {
        int p = t + 1024 * i;
#pragma unroll
        for (int o = 0; o < 3; o++) {
            double y = ((x[i][o] - par[o]) * par[3 + o]) * gv[o] + bv[o];
            y = (y > 0.0) ? y : 0.0;
            nxd[p * 3 + o] = y;
            nxf[p * 3 + o] = (float)y;
        }
    }
}

// ---------------- K2: ball query (first NS in index order within radius) ----------------
__global__ __launch_bounds__(256) void k_ballq(const float* __restrict__ bbxyz,
                                               const double* __restrict__ nxd,
                                               int* __restrict__ idxo) {
#pragma clang fp contract(off)
    int t = threadIdx.x;
    int wv = t >> 6, lane = t & 63;
    int q = blockIdx.x * 4 + wv;                   // bp index
    int b = q >> 11;                               // P = 2048
    double qx = nxd[q * 3 + 0], qy = nxd[q * 3 + 1], qz = nxd[q * 3 + 2];
    const double R2 = 0.8 * 0.8;
    // early-out: ball cannot intersect backbone cube [-1,1]^3 -> zero neighbors,
    // reference pads with index 0 in that case.
    {
        double ex = fmax(fmax(qx - 1.0, -1.0 - qx), 0.0);
        double ey = fmax(fmax(qy - 1.0, -1.0 - qy), 0.0);
        double ez = fmax(fmax(qz - 1.0, -1.0 - qz), 0.0);
        if (ex * ex + ey * ey + ez * ez >= R2) {
            if (lane < NS) idxo[q * NS + lane] = 0;
            return;
        }
    }
    const float* base = bbxyz + (size_t)b * N * 3;
    int found = 0, firstn = -1;
    for (int chunk = 0; chunk < N / 64; chunk++) {
        int n = chunk * 64 + lane;
        float bx = base[n * 3 + 0], by = base[n * 3 + 1], bz = base[n * 3 + 2];
        double dx = qx - (double)bx, dy = qy - (double)by, dz = qz - (double)bz;
        double d2 = (dx * dx + dy * dy) + dz * dz;
        bool within = d2 < R2;
        unsigned long long mask = __ballot(within);
        if (firstn < 0 && mask != 0ull) firstn = chunk * 64 + (__ffsll(mask) - 1);
        if (within) {
            int rank = found + __popcll(mask & ((1ull << lane) - 1ull));
            if (rank < NS) idxo[q * NS + rank] = n;
        }
        found += __popcll(mask);
        if (found >= NS) break;
    }
    if (found < NS) {
        int padv = (found == 0) ? 0 : firstn;
        if (lane >= found && lane < NS) idxo[q * NS + lane] = padv;
    }
}

// ---------------- K3: MFMA grouped 1x1 conv, transposed mapping + dbuf pipeline ----
// 512 blocks x 4 groups x 4 bp. A = G (m=samples), B = W^T (n=couts): C rows are
// samples -> max over samples = 7 in-lane fmax + xor16/xor32. BN sums accumulate
// in registers across groups, one butterfly per block. Feats staged to LDS via
// global_load_lds(16B) double-buffered: stage(g+1) issued after the barrier,
// compute(g) runs under it. xyz = ks=4 A-frag built in registers (q==0 lanes).
__global__ __launch_bounds__(256, 2) void k_mlp_mfma(
        const float* __restrict__ bbxyz,
        const unsigned short* __restrict__ featT,
        const unsigned short* __restrict__ wswz,
        const float* __restrict__ nxf,
        const int* __restrict__ idx,
        float* __restrict__ ymax,
        float* __restrict__ partial) {
    // G[buf][(mt*4+ks)*64 + lane][8]: element (s = mt*16+(lane&15), k' = ks*32+(lane>>4)*8+j)
    __shared__ alignas(16) unsigned short G[2][8 * 4 * 64 * 8];   // 2 x 32768 B
    int t = threadIdx.x, lane = t & 63, w = t >> 6;
    int q = lane >> 4, c16 = lane & 15;
    int blk = blockIdx.x;
    int bpbase = blk * (BPB * GRP);
    const bf16x8* wp = (const bf16x8*)wswz;

    int n_cur[8], n_nxt[8];
    // group-0 index loads + stage
#pragma unroll
    for (int mt = 0; mt < 8; mt++)
        n_cur[mt] = idx[(bpbase + (mt >> 1)) * NS + (mt & 1) * 16 + c16];
    {
        int bp0 = bpbase;
#pragma unroll
        for (int cc = 0; cc < 2; cc++) {
            int mt = 2 * w + cc;
            int bp = bp0 + (mt >> 1);
            const unsigned short* row = featT + ((size_t)(bp >> 11) * N + n_cur[mt]) * C + q * 8;
#pragma unroll
            for (int ks = 0; ks < 4; ks++)
                GLOBAL_LOAD_LDS16(row + ks * 32, &G[0][(mt * 4 + ks) * 512]);
        }
    }

    float smA[4] = {0.f, 0.f, 0.f, 0.f}, sqA[4] = {0.f, 0.f, 0.f, 0.f};

    for (int g = 0; g < GRP; g++) {
        int buf = g & 1;
        int bp0 = bpbase + g * BPB;
        if (g + 1 < GRP) {
            int bp0n = bpbase + (g + 1) * BPB;
#pragma unroll
            for (int mt = 0; mt < 8; mt++)
                n_nxt[mt] = idx[(bp0n + (mt >> 1)) * NS + (mt & 1) * 16 + c16];
        }
        __syncthreads();   // stage(g) drained; compute(g-1) reads of buf^1 done
        if (g + 1 < GRP) {
            int bp0n = bpbase + (g + 1) * BPB;
#pragma unroll
            for (int cc = 0; cc < 2; cc++) {
                int mt = 2 * w + cc;
                int bp = bp0n + (mt >> 1);
                const unsigned short* row = featT + ((size_t)(bp >> 11) * N + n_nxt[mt]) * C + q * 8;
#pragma unroll
                for (int ks = 0; ks < 4; ks++)
                    GLOBAL_LOAD_LDS16(row + ks * 32, &G[buf ^ 1][(mt * 4 + ks) * 512]);
            }
        }

        // ---- compute(g) on G[buf] ----
        f32x4 acc[8][4];
#pragma unroll
        for (int mt = 0; mt < 8; mt++)
#pragma unroll
            for (int nt = 0; nt < 4; nt++) acc[mt][nt] = (f32x4){0.f, 0.f, 0.f, 0.f};

#pragma unroll
        for (int ks = 0; ks < 4; ks++) {
            bf16x8 ag[8];
#pragma unroll
            for (int mt = 0; mt < 8; mt++)
                ag[mt] = *(const bf16x8*)&G[buf][((mt * 4 + ks) * 64 + lane) * 8];
#pragma unroll
            for (int nt = 0; nt < 4; nt++) {
                bf16x8 wf = wp[((w * 4 + nt) * 5 + ks) * 64 + lane];
#pragma unroll
                for (int mt = 0; mt < 8; mt++)
                    acc[mt][nt] = __builtin_amdgcn_mfma_f32_16x16x32_bf16(ag[mt], wf, acc[mt][nt], 0, 0, 0);
            }
        }
        // ks = 4: xyz A-frags in registers (q==0: j0..2 = recentered xyz, else 0)
        {
            bf16x8 agx[8];
#pragma unroll
            for (int mt = 0; mt < 8; mt++) {
                int bp = bp0 + (mt >> 1);
                unsigned u01 = 0, u23 = 0;
                if (q == 0) {
                    const float* src = bbxyz + ((size_t)(bp >> 11) * N + n_cur[mt]) * 3;
                    const float* ctr = nxf + bp * 3;
                    u01 = (unsigned)f2bf(src[0] - ctr[0]) | ((unsigned)f2bf(src[1] - ctr[1]) << 16);
                    u23 = (unsigned)f2bf(src[2] - ctr[2]);
                }
                union { int4 i; bf16x8 h; } u;
                u.i = make_int4((int)u01, (int)u23, 0, 0);
                agx[mt] = u.h;
            }
#pragma unroll
            for (int nt = 0; nt < 4; nt++) {
                bf16x8 wf = wp[((w * 4 + nt) * 5 + 4) * 64 + lane];
#pragma unroll
                for (int mt = 0; mt < 8; mt++)
                    acc[mt][nt] = __builtin_amdgcn_mfma_f32_16x16x32_bf16(agx[mt], wf, acc[mt][nt], 0, 0, 0);
            }
        }

        // ---- epilogue: max over 32 samples (2 m-tiles) per bp; sums accumulate ----
#pragma unroll
        for (int pm = 0; pm < BPB; pm++) {
            int bp = bp0 + pm;
#pragma unroll
            for (int nt = 0; nt < 4; nt++) {
                f32x4 a = acc[2 * pm][nt], c = acc[2 * pm + 1][nt];
                float mx = fmaxf(fmaxf(fmaxf(a[0], a[1]), fmaxf(a[2], a[3])),
                                 fmaxf(fmaxf(c[0], c[1]), fmaxf(c[2], c[3])));
                smA[nt] += ((a[0] + a[1]) + (a[2] + a[3])) + ((c[0] + c[1]) + (c[2] + c[3]));
                sqA[nt] += ((a[0] * a[0] + a[1] * a[1]) + (a[2] * a[2] + a[3] * a[3])) +
                           ((c[0] * c[0] + c[1] * c[1]) + (c[2] * c[2] + c[3] * c[3]));
                mx = fmaxf(mx, __shfl_xor(mx, 16, 64));
                mx = fmaxf(mx, __shfl_xor(mx, 32, 64));
                if (q == 0)
                    ymax[(size_t)bp * COUT + w * 64 + nt * 16 + c16] = mx;
            }
        }
#pragma unroll
        for (int mt = 0; mt < 8; mt++) n_cur[mt] = n_nxt[mt];
    }

    // ---- block-level sum butterfly (once) ----
#pragma unroll
    for (int nt = 0; nt < 4; nt++) {
        float sm = smA[nt], sq = sqA[nt];
        sm += __shfl_xor(sm, 16, 64);
        sm += __shfl_xor(sm, 32, 64);
        sq += __shfl_xor(sq, 16, 64);
        sq += __shfl_xor(sq, 32, 64);
        if (q == 0) {
            int cout = w * 64 + nt * 16 + c16;
            partial[(size_t)blk * 512 + cout] = sm;
            partial[(size_t)blk * 512 + 256 + cout] = sq;
        }
    }
}

// ---------------- K4a: reduce partial (512x512) -> (128x512) ----------------
__global__ __launch_bounds__(256) void k_red(const float* __restrict__ partial,
                                             float* __restrict__ p2) {
    int t = threadIdx.x, j = blockIdx.x;
    const float* row = partial + (size_t)j * 4 * 512;
    float s0 = 0.f, s1 = 0.f;
    for (int r = 0; r < 4; r++) {
        s0 += row[r * 512 + t];
        s1 += row[r * 512 + 256 + t];
    }
    p2[j * 512 + t] = s0;
    p2[j * 512 + 256 + t] = s1;
}

// ---------------- K4b: final stats -> per-channel scale/bias ----------------
__global__ __launch_bounds__(256) void k_stats(const float* __restrict__ p2,
                                               const float* __restrict__ gam,
                                               const float* __restrict__ bet,
                                               float* __restrict__ ab) {
    int c = threadIdx.x;
    double sm = 0.0, sq = 0.0;
    for (int r = 0; r < 128; r++) {
        sm += (double)p2[r * 512 + c];
        sq += (double)p2[r * 512 + 256 + c];
    }
    const double cnt = (double)BP * (double)NS;    // 262144
    double mean = sm / cnt;
    double var = sq / cnt - mean * mean;
    double a = (double)gam[c] / sqrt(var + 1e-5);  // gamma==1 -> a>0 always
    double bb = (double)bet[c] - mean * a;
    ab[c] = (float)a;
    ab[256 + c] = (float)bb;
}

// ---------------- K5: out = relu(a * ymax + b)  (a>0 for all channels) ----------------
__global__ __launch_bounds__(256) void k_final(const float* __restrict__ ymax,
                                               const float* __restrict__ ab,
                                               float* __restrict__ out) {
    int e = blockIdx.x * 256 + threadIdx.x;
    int c = e & 255;
    out[e] = fmaxf(ab[c] * ymax[e] + ab[256 + c], 0.f);
}

extern "C" void kernel_launch(void* const* d_in, const int* in_sizes, int n_in,
                              void* d_out, int out_size, void* d_ws, size_t ws_size,
                              hipStream_t stream) {
    const float* ffps  = (const float*)d_in[0];
    const float* bbxyz = (const float*)d_in[1];
    const float* feat  = (const float*)d_in[2];
    const float* wsh   = (const float*)d_in[3];
    const float* gsh   = (const float*)d_in[4];
    const float* bsh   = (const float*)d_in[5];
    const float* wml   = (const float*)d_in[6];
    const float* gml   = (const float*)d_in[7];
    const float* bml   = (const float*)d_in[8];
    float* out = (float*)d_out;
    char* ws = (char*)d_ws;
    if (ws_size < WS_NEED) return;

    unsigned short* featT = (unsigned short*)(ws + OFF_FEATT);
    unsigned short* wswz  = (unsigned short*)(ws + OFF_WSWZ);
    double*         nxd   = (double*)(ws + OFF_NXD);
    float*          nxf   = (float*)(ws + OFF_NXF);
    int*            idx   = (int*)(ws + OFF_IDX);
    float*          ymax  = (float*)(ws + OFF_YMAX);
    float*          part  = (float*)(ws + OFF_PART);
    float*          p2    = (float*)(ws + OFF_P2);
    float*          ab    = (float*)(ws + OFF_AB);

    k_transpose<<<dim3(N / 32, C / 64, B), dim3(32, 8, 1), 0, stream>>>(feat, featT);
    k_wswz<<<dim3(160), dim3(256), 0, stream>>>(wml, wswz);
    k_shift<<<dim3(1), dim3(1024), 0, stream>>>(ffps, wsh, gsh, bsh, nxd, nxf);
    k_ballq<<<dim3(BP / 4), dim3(256), 0, stream>>>(bbxyz, nxd, idx);
    k_mlp_mfma<<<dim3(NBLK), dim3(256), 0, stream>>>(bbxyz, featT, wswz, nxf, idx, ymax, part);
    k_red<<<dim3(128), dim3(256), 0, stream>>>(part, p2);
    k_stats<<<dim3(1), dim3(256), 0, stream>>>(p2, gml, bml, ab);
    k_final<<<dim3(BP * COUT / 256), dim3(256), 0, stream>>>(ymax, ab, out);
}

// Round 5
// 190.189 us; speedup vs baseline: 1.2075x; 1.2075x over previous
//
#include <hip/hip_runtime.h>
#include <math.h>

namespace {
constexpr int B    = 4;
constexpr int N    = 8192;
constexpr int P    = 2048;
constexpr int C    = 128;
constexpr int COUT = 256;
constexpr int NS   = 32;
constexpr int BP   = B * P;     // 8192
constexpr int BPB  = 2;         // bp per group (4 m-tiles -> acc[4][4] = 64 VGPRs)
constexpr int GRP  = 8;         // groups per block
constexpr int NBLK = BP / (BPB * GRP); // 512 blocks (2/CU)

// ---- workspace layout (bytes, all 256-aligned) ----
constexpr size_t OFF_FEATT = 0;                          // B*N*C bf16    = 8388608
constexpr size_t OFF_WSWZ  = 8388608;                    // 40960 bf16    = 81920
constexpr size_t OFF_NXD   = 8470528;                    // 8192*3 f64    = 196608
constexpr size_t OFF_NXF   = 8667136;                    // 8192*3 f32    = 98304
constexpr size_t OFF_IDX   = 8765440;                    // 8192*32 i32   = 1048576
constexpr size_t OFF_YMAX  = 9814016;                    // 8192*256 f32  = 8388608
constexpr size_t OFF_PART  = 18202624;                   // 512*512 f32   = 1048576
constexpr size_t OFF_P2    = 19251200;                   // 128*512 f32   = 262144
constexpr size_t OFF_AB    = 19513344;                   // 512 f32       = 2048
constexpr size_t WS_NEED   = 19515392;                   // ~18.6 MB
} // namespace

typedef short bf16x8 __attribute__((ext_vector_type(8)));
typedef float f32x4  __attribute__((ext_vector_type(4)));

typedef const __attribute__((address_space(1))) void gas_void;
typedef __attribute__((address_space(3))) void las_void;
#define GLOBAL_LOAD_LDS16(gp, lp) \
    __builtin_amdgcn_global_load_lds((gas_void*)(gp), (las_void*)(lp), 16, 0, 0)

__device__ inline unsigned short f2bf(float f) {
    unsigned u = __float_as_uint(f);
    unsigned r = u + 0x7fffu + ((u >> 16) & 1u);
    return (unsigned short)(r >> 16);
}

// ---------------- K0a: transpose features (B,C,N) f32 -> (B,N,C) bf16 ----------------
__global__ __launch_bounds__(256) void k_transpose(const float* __restrict__ feat,
                                                   unsigned short* __restrict__ featT) {
    __shared__ float tile[64][33];
    int tx = threadIdx.x, ty = threadIdx.y;        // 32 x 8
    int n0 = blockIdx.x * 32, c0 = blockIdx.y * 64, b = blockIdx.z;
    const float* src = feat + ((size_t)b * C + c0) * N + n0;
#pragma unroll
    for (int j = 0; j < 8; j++) tile[ty + 8 * j][tx] = src[(size_t)(ty + 8 * j) * N + tx];
    __syncthreads();
#pragma unroll
    for (int j = 0; j < 4; j++) {
        int n = ty + 8 * j;
        unsigned v = (unsigned)f2bf(tile[2 * tx][n]) | ((unsigned)f2bf(tile[2 * tx + 1][n]) << 16);
        *(unsigned*)&featT[((size_t)b * N + n0 + n) * C + c0 + 2 * tx] = v;
    }
}

// ---------------- K0b: swizzle w_mlp into MFMA fragment order (bf16) ----------------
// wswz[rt(16)][ks(5)][lane(64)][j(8)]; element = W[rt*16+(lane&15)][k'] with
// k' = ks*32+(lane>>4)*8+j; k-map: 0..127 -> w col 3+k' (feats); 128..130 -> w col
// 0..2 (xyz); else 0. Used as B-fragment (n=cout); A/B fragment index maps coincide.
__global__ __launch_bounds__(256) void k_wswz(const float* __restrict__ w,
                                              unsigned short* __restrict__ wswz) {
    int i = blockIdx.x * 256 + threadIdx.x;        // < 40960
    int j = i & 7;
    int lane = (i >> 3) & 63;
    int rest = i >> 9;                             // 0..79
    int ks = rest % 5, rt = rest / 5;
    int cout = rt * 16 + (lane & 15);
    int k = ks * 32 + (lane >> 4) * 8 + j;
    float v = 0.f;
    if (k < 128) v = w[cout * 131 + 3 + k];
    else if (k < 131) v = w[cout * 131 + (k - 128)];
    wswz[i] = f2bf(v);
}

// ---------------- K1: shift conv + BN(train) + ReLU, fp64 to match np ref ----------------
__global__ __launch_bounds__(1024) void k_shift(const float* __restrict__ ffps,
                                                const float* __restrict__ wsh,
                                                const float* __restrict__ gam,
                                                const float* __restrict__ bet,
                                                double* __restrict__ nxd,
                                                float* __restrict__ nxf) {
#pragma clang fp contract(off)
    __shared__ double red[6][1024];
    __shared__ double par[6];
    int t = threadIdx.x;
    double w[9];
#pragma unroll
    for (int i = 0; i < 9; i++) w[i] = (double)wsh[i];
    double x[8][3];
    double s[3] = {0, 0, 0}, sq[3] = {0, 0, 0};
#pragma unroll
    for (int i = 0; i < 8; i++) {
        int p = t + 1024 * i;
        double f0 = (double)ffps[p * 3 + 0];
        double f1 = (double)ffps[p * 3 + 1];
        double f2 = (double)ffps[p * 3 + 2];
#pragma unroll
        for (int o = 0; o < 3; o++) {
            double xo = (w[o * 3 + 0] * f0 + w[o * 3 + 1] * f1) + w[o * 3 + 2] * f2;
            x[i][o] = xo;
            s[o] += xo;
            sq[o] += xo * xo;
        }
    }
#pragma unroll
    for (int o = 0; o < 3; o++) { red[o][t] = s[o]; red[3 + o][t] = sq[o]; }
    for (int off = 512; off > 0; off >>= 1) {
        __syncthreads();
        if (t < off) {
#pragma unroll
            for (int j = 0; j < 6; j++) red[j][t] += red[j][t + off];
        }
    }
    __syncthreads();
    if (t == 0) {
#pragma unroll
        for (int o = 0; o < 3; o++) {
            double m = red[o][0] / (double)BP;
            double v = red[3 + o][0] / (double)BP - m * m;
            par[o] = m;
            par[3 + o] = 1.0 / sqrt(v + 1e-5);
        }
    }
    __syncthreads();
    double gv[3] = {(double)gam[0], (double)gam[1], (double)gam[2]};
    double bv[3] = {(double)bet[0], (double)bet[1], (double)bet[2]};
#pragma unroll
    for (int i = 0; i < 8; i++) {
        int p = t + 1024 * i;
#pragma unroll
        for (int o = 0; o < 3; o++) {
            double y = ((x[i][o] - par[o]) * par[3 + o]) * gv[o] + bv[o];
            y = (y > 0.0) ? y : 0.0;
            nxd[p * 3 + o] = y;
            nxf[p * 3 + o] = (float)y;
        }
    }
}

// ---------------- K2: ball query (first NS in index order within radius) ----------------
__global__ __launch_bounds__(256) void k_ballq(const float* __restrict__ bbxyz,
                                               const double* __restrict__ nxd,
                                               int* __restrict__ idxo) {
#pragma clang fp contract(off)
    int t = threadIdx.x;
    int wv = t >> 6, lane = t & 63;
    int q = blockIdx.x * 4 + wv;                   // bp index
    int b = q >> 11;                               // P = 2048
    double qx = nxd[q * 3 + 0], qy = nxd[q * 3 + 1], qz = nxd[q * 3 + 2];
    const double R2 = 0.8 * 0.8;
    // early-out: ball cannot intersect backbone cube [-1,1]^3 -> zero neighbors,
    // reference pads with index 0 in that case.
    {
        double ex = fmax(fmax(qx - 1.0, -1.0 - qx), 0.0);
        double ey = fmax(fmax(qy - 1.0, -1.0 - qy), 0.0);
        double ez = fmax(fmax(qz - 1.0, -1.0 - qz), 0.0);
        if (ex * ex + ey * ey + ez * ez >= R2) {
            if (lane < NS) idxo[q * NS + lane] = 0;
            return;
        }
    }
    const float* base = bbxyz + (size_t)b * N * 3;
    int found = 0, firstn = -1;
    for (int chunk = 0; chunk < N / 64; chunk++) {
        int n = chunk * 64 + lane;
        float bx = base[n * 3 + 0], by = base[n * 3 + 1], bz = base[n * 3 + 2];
        double dx = qx - (double)bx, dy = qy - (double)by, dz = qz - (double)bz;
        double d2 = (dx * dx + dy * dy) + dz * dz;
        bool within = d2 < R2;
        unsigned long long mask = __ballot(within);
        if (firstn < 0 && mask != 0ull) firstn = chunk * 64 + (__ffsll(mask) - 1);
        if (within) {
            int rank = found + __popcll(mask & ((1ull << lane) - 1ull));
            if (rank < NS) idxo[q * NS + rank] = n;
        }
        found += __popcll(mask);
        if (found >= NS) break;
    }
    if (found < NS) {
        int padv = (found == 0) ? 0 : firstn;
        if (lane >= found && lane < NS) idxo[q * NS + lane] = padv;
    }
}

// ---------------- K3: MFMA grouped 1x1 conv, pipelined, register-budgeted ----------
// 512 blocks x 8 groups x 2 bp. A = G (m=samples), B = W^T (n=couts). W fragments
// (wreg[5][4], 80 VGPRs) loaded ONCE and live across all groups; acc[4][4] = 64
// VGPRs; total deliberate ~200 < 256 (launch_bounds(256,2)) -> no spill (R4 bug:
// compiler hoisted W over an acc[8][4] tile -> 128 VGPR cap blown -> 170 MB of
// scratch HBM traffic). Feats double-buffered via global_load_lds(16B); each wave
// stages m-tile mt==w (4 loads/group). xyz enters as in-register ks=4 A-frag.
__global__ __launch_bounds__(256, 2) void k_mlp_mfma(
        const float* __restrict__ bbxyz,
        const unsigned short* __restrict__ featT,
        const unsigned short* __restrict__ wswz,
        const float* __restrict__ nxf,
        const int* __restrict__ idx,
        float* __restrict__ ymax,
        float* __restrict__ partial) {
    // G[buf][(mt*4+ks)*64 + lane][8]: element (s = mt*16+(lane&15), k' = ks*32+(lane>>4)*8+j)
    __shared__ alignas(16) unsigned short G[2][4 * 4 * 64 * 8];   // 2 x 16384 B
    int t = threadIdx.x, lane = t & 63, w = t >> 6;
    int q = lane >> 4, c16 = lane & 15;
    int blk = blockIdx.x;
    int bpbase = blk * (BPB * GRP);                // 16 bp per block
    const bf16x8* wp = (const bf16x8*)wswz;

    // ---- W fragments resident in registers for the whole kernel ----
    bf16x8 wreg[5][4];
#pragma unroll
    for (int ks = 0; ks < 5; ks++)
#pragma unroll
        for (int nt = 0; nt < 4; nt++)
            wreg[ks][nt] = wp[((w * 4 + nt) * 5 + ks) * 64 + lane];

    int n_cur[4], n_nxt[4];
#pragma unroll
    for (int mt = 0; mt < 4; mt++)
        n_cur[mt] = idx[(bpbase + (mt >> 1)) * NS + (mt & 1) * 16 + c16];
    {   // stage group 0: wave w stages m-tile w
        int bp = bpbase + (w >> 1);
        const unsigned short* row = featT + ((size_t)(bp >> 11) * N + n_cur[w]) * C + q * 8;
#pragma unroll
        for (int ks = 0; ks < 4; ks++)
            GLOBAL_LOAD_LDS16(row + ks * 32, &G[0][(w * 4 + ks) * 512]);
    }

    float smA[4] = {0.f, 0.f, 0.f, 0.f}, sqA[4] = {0.f, 0.f, 0.f, 0.f};

    for (int g = 0; g < GRP; g++) {
        int buf = g & 1;
        int bp0 = bpbase + g * BPB;
        if (g + 1 < GRP) {
#pragma unroll
            for (int mt = 0; mt < 4; mt++)
                n_nxt[mt] = idx[(bp0 + BPB + (mt >> 1)) * NS + (mt & 1) * 16 + c16];
        }
        __syncthreads();   // stage(g) drained; compute(g-1) reads of buf^1 done
        if (g + 1 < GRP) {
            int bp = bp0 + BPB + (w >> 1);
            const unsigned short* row = featT + ((size_t)(bp >> 11) * N + n_nxt[w]) * C + q * 8;
#pragma unroll
            for (int ks = 0; ks < 4; ks++)
                GLOBAL_LOAD_LDS16(row + ks * 32, &G[buf ^ 1][(w * 4 + ks) * 512]);
        }

        // ---- compute(g) on G[buf] ----
        f32x4 acc[4][4];
#pragma unroll
        for (int mt = 0; mt < 4; mt++)
#pragma unroll
            for (int nt = 0; nt < 4; nt++) acc[mt][nt] = (f32x4){0.f, 0.f, 0.f, 0.f};

#pragma unroll
        for (int ks = 0; ks < 4; ks++) {
            bf16x8 ag[4];
#pragma unroll
            for (int mt = 0; mt < 4; mt++)
                ag[mt] = *(const bf16x8*)&G[buf][((mt * 4 + ks) * 64 + lane) * 8];
#pragma unroll
            for (int nt = 0; nt < 4; nt++)
#pragma unroll
                for (int mt = 0; mt < 4; mt++)
                    acc[mt][nt] = __builtin_amdgcn_mfma_f32_16x16x32_bf16(ag[mt], wreg[ks][nt], acc[mt][nt], 0, 0, 0);
        }
        {   // ks = 4: xyz A-frags in registers (q==0: j0..2 = recentered xyz, else 0)
            bf16x8 agx[4];
#pragma unroll
            for (int mt = 0; mt < 4; mt++) {
                int bp = bp0 + (mt >> 1);
                unsigned u01 = 0, u23 = 0;
                if (q == 0) {
                    const float* src = bbxyz + ((size_t)(bp >> 11) * N + n_cur[mt]) * 3;
                    const float* ctr = nxf + bp * 3;
                    u01 = (unsigned)f2bf(src[0] - ctr[0]) | ((unsigned)f2bf(src[1] - ctr[1]) << 16);
                    u23 = (unsigned)f2bf(src[2] - ctr[2]);
                }
                union { int4 i; bf16x8 h; } u;
                u.i = make_int4((int)u01, (int)u23, 0, 0);
                agx[mt] = u.h;
            }
#pragma unroll
            for (int nt = 0; nt < 4; nt++)
#pragma unroll
                for (int mt = 0; mt < 4; mt++)
                    acc[mt][nt] = __builtin_amdgcn_mfma_f32_16x16x32_bf16(agx[mt], wreg[4][nt], acc[mt][nt], 0, 0, 0);
        }

        // ---- epilogue: max over 32 samples (2 m-tiles) per bp; sums accumulate ----
#pragma unroll
        for (int pm = 0; pm < BPB; pm++) {
            int bp = bp0 + pm;
#pragma unroll
            for (int nt = 0; nt < 4; nt++) {
                f32x4 a = acc[2 * pm][nt], c = acc[2 * pm + 1][nt];
                float mx = fmaxf(fmaxf(fmaxf(a[0], a[1]), fmaxf(a[2], a[3])),
                                 fmaxf(fmaxf(c[0], c[1]), fmaxf(c[2], c[3])));
                smA[nt] += ((a[0] + a[1]) + (a[2] + a[3])) + ((c[0] + c[1]) + (c[2] + c[3]));
                sqA[nt] += ((a[0] * a[0] + a[1] * a[1]) + (a[2] * a[2] + a[3] * a[3])) +
                           ((c[0] * c[0] + c[1] * c[1]) + (c[2] * c[2] + c[3] * c[3]));
                mx = fmaxf(mx, __shfl_xor(mx, 16, 64));
                mx = fmaxf(mx, __shfl_xor(mx, 32, 64));
                if (q == 0)
                    ymax[(size_t)bp * COUT + w * 64 + nt * 16 + c16] = mx;
            }
        }
#pragma unroll
        for (int mt = 0; mt < 4; mt++) n_cur[mt] = n_nxt[mt];
    }

    // ---- block-level sum butterfly (once) ----
#pragma unroll
    for (int nt = 0; nt < 4; nt++) {
        float sm = smA[nt], sq = sqA[nt];
        sm += __shfl_xor(sm, 16, 64);
        sm += __shfl_xor(sm, 32, 64);
        sq += __shfl_xor(sq, 16, 64);
        sq += __shfl_xor(sq, 32, 64);
        if (q == 0) {
            int cout = w * 64 + nt * 16 + c16;
            partial[(size_t)blk * 512 + cout] = sm;
            partial[(size_t)blk * 512 + 256 + cout] = sq;
        }
    }
}

// ---------------- K4a: reduce partial (512x512) -> (128x512) ----------------
__global__ __launch_bounds__(256) void k_red(const float* __restrict__ partial,
                                             float* __restrict__ p2) {
    int t = threadIdx.x, j = blockIdx.x;
    const float* row = partial + (size_t)j * 4 * 512;
    float s0 = 0.f, s1 = 0.f;
    for (int r = 0; r < 4; r++) {
        s0 += row[r * 512 + t];
        s1 += row[r * 512 + 256 + t];
    }
    p2[j * 512 + t] = s0;
    p2[j * 512 + 256 + t] = s1;
}

// ---------------- K4b: final stats -> per-channel scale/bias ----------------
__global__ __launch_bounds__(256) void k_stats(const float* __restrict__ p2,
                                               const float* __restrict__ gam,
                                               const float* __restrict__ bet,
                                               float* __restrict__ ab) {
    int c = threadIdx.x;
    double sm = 0.0, sq = 0.0;
    for (int r = 0; r < 128; r++) {
        sm += (double)p2[r * 512 + c];
        sq += (double)p2[r * 512 + 256 + c];
    }
    const double cnt = (double)BP * (double)NS;    // 262144
    double mean = sm / cnt;
    double var = sq / cnt - mean * mean;
    double a = (double)gam[c] / sqrt(var + 1e-5);  // gamma==1 -> a>0 always
    double bb = (double)bet[c] - mean * a;
    ab[c] = (float)a;
    ab[256 + c] = (float)bb;
}

// ---------------- K5: out = relu(a * ymax + b)  (a>0 for all channels) ----------------
__global__ __launch_bounds__(256) void k_final(const float* __restrict__ ymax,
                                               const float* __restrict__ ab,
                                               float* __restrict__ out) {
    int e = blockIdx.x * 256 + threadIdx.x;
    int c = e & 255;
    out[e] = fmaxf(ab[c] * ymax[e] + ab[256 + c], 0.f);
}

extern "C" void kernel_launch(void* const* d_in, const int* in_sizes, int n_in,
                              void* d_out, int out_size, void* d_ws, size_t ws_size,
                              hipStream_t stream) {
    const float* ffps  = (const float*)d_in[0];
    const float* bbxyz = (const float*)d_in[1];
    const float* feat  = (const float*)d_in[2];
    const float* wsh   = (const float*)d_in[3];
    const float* gsh   = (const float*)d_in[4];
    const float* bsh   = (const float*)d_in[5];
    const float* wml   = (const float*)d_in[6];
    const float* gml   = (const float*)d_in[7];
    const float* bml   = (const float*)d_in[8];
    float* out = (float*)d_out;
    char* ws = (char*)d_ws;
    if (ws_size < WS_NEED) return;

    unsigned short* featT = (unsigned short*)(ws + OFF_FEATT);
    unsigned short* wswz  = (unsigned short*)(ws + OFF_WSWZ);
    double*         nxd   = (double*)(ws + OFF_NXD);
    float*          nxf   = (float*)(ws + OFF_NXF);
    int*            idx   = (int*)(ws + OFF_IDX);
    float*          ymax  = (float*)(ws + OFF_YMAX);
    float*          part  = (float*)(ws + OFF_PART);
    float*          p2    = (float*)(ws + OFF_P2);
    float*          ab    = (float*)(ws + OFF_AB);

    k_transpose<<<dim3(N / 32, C / 64, B), dim3(32, 8, 1), 0, stream>>>(feat, featT);
    k_wswz<<<dim3(160), dim3(256), 0, stream>>>(wml, wswz);
    k_shift<<<dim3(1), dim3(1024), 0, stream>>>(ffps, wsh, gsh, bsh, nxd, nxf);
    k_ballq<<<dim3(BP / 4), dim3(256), 0, stream>>>(bbxyz, nxd, idx);
    k_mlp_mfma<<<dim3(NBLK), dim3(256), 0, stream>>>(bbxyz, featT, wswz, nxf, idx, ymax, part);
    k_red<<<dim3(128), dim3(256), 0, stream>>>(part, p2);
    k_stats<<<dim3(1), dim3(256), 0, stream>>>(p2, gml, bml, ab);
    k_final<<<dim3(BP * COUT / 256), dim3(256), 0, stream>>>(ymax, ab, out);
}

// Round 6
// 171.316 us; speedup vs baseline: 1.3406x; 1.1102x over previous
//
#include <hip/hip_runtime.h>
#include <math.h>

namespace {
constexpr int B    = 4;
constexpr int N    = 8192;
constexpr int P    = 2048;
constexpr int C    = 128;
constexpr int COUT = 256;
constexpr int NS   = 32;
constexpr int BP   = B * P;     // 8192
constexpr int BPB  = 2;         // bp per group (4 m-tiles -> acc[4][4] = 64 VGPRs)
constexpr int GRP  = 8;         // groups per block
constexpr int NBLK = BP / (BPB * GRP); // 512 blocks (2/CU)

// ---- workspace layout (bytes, all 256-aligned) ----
constexpr size_t OFF_FEATT = 0;                          // B*N*C bf16    = 8388608
constexpr size_t OFF_WSWZ  = 8388608;                    // 40960 bf16    = 81920
constexpr size_t OFF_NXD   = 8470528;                    // 8192*3 f64    = 196608
constexpr size_t OFF_NXF   = 8667136;                    // 8192*3 f32    = 98304
constexpr size_t OFF_IDX   = 8765440;                    // 8192*32 i32   = 1048576
constexpr size_t OFF_YMAX  = 9814016;                    // 8192*256 f32  = 8388608
constexpr size_t OFF_PART  = 18202624;                   // 512*512 f32   = 1048576
constexpr size_t OFF_P2    = 19251200;                   // 128*512 f32   = 262144
constexpr size_t OFF_AB    = 19513344;                   // 512 f32       = 2048
constexpr size_t WS_NEED   = 19515392;                   // ~18.6 MB
} // namespace

typedef short bf16x8 __attribute__((ext_vector_type(8)));
typedef float f32x4  __attribute__((ext_vector_type(4)));

typedef const __attribute__((address_space(1))) void gas_void;
typedef __attribute__((address_space(3))) void las_void;
#define GLOBAL_LOAD_LDS16(gp, lp) \
    __builtin_amdgcn_global_load_lds((gas_void*)(gp), (las_void*)(lp), 16, 0, 0)

__device__ inline unsigned short f2bf(float f) {
    unsigned u = __float_as_uint(f);
    unsigned r = u + 0x7fffu + ((u >> 16) & 1u);
    return (unsigned short)(r >> 16);
}

// ---------------- K0a: transpose features (B,C,N) f32 -> (B,N,C) bf16 ----------------
__global__ __launch_bounds__(256) void k_transpose(const float* __restrict__ feat,
                                                   unsigned short* __restrict__ featT) {
    __shared__ float tile[64][33];
    int tx = threadIdx.x, ty = threadIdx.y;        // 32 x 8
    int n0 = blockIdx.x * 32, c0 = blockIdx.y * 64, b = blockIdx.z;
    const float* src = feat + ((size_t)b * C + c0) * N + n0;
#pragma unroll
    for (int j = 0; j < 8; j++) tile[ty + 8 * j][tx] = src[(size_t)(ty + 8 * j) * N + tx];
    __syncthreads();
#pragma unroll
    for (int j = 0; j < 4; j++) {
        int n = ty + 8 * j;
        unsigned v = (unsigned)f2bf(tile[2 * tx][n]) | ((unsigned)f2bf(tile[2 * tx + 1][n]) << 16);
        *(unsigned*)&featT[((size_t)b * N + n0 + n) * C + c0 + 2 * tx] = v;
    }
}

// ---------------- K0b: swizzle w_mlp into MFMA fragment order (bf16) ----------------
// wswz[rt(16)][ks(5)][lane(64)][j(8)]; element = W[rt*16+(lane&15)][k'] with
// k' = ks*32+(lane>>4)*8+j; k-map: 0..127 -> w col 3+k' (feats); 128..130 -> w col
// 0..2 (xyz); else 0. Used as B-fragment (n=cout); A/B fragment index maps coincide.
__global__ __launch_bounds__(256) void k_wswz(const float* __restrict__ w,
                                              unsigned short* __restrict__ wswz) {
    int i = blockIdx.x * 256 + threadIdx.x;        // < 40960
    int j = i & 7;
    int lane = (i >> 3) & 63;
    int rest = i >> 9;                             // 0..79
    int ks = rest % 5, rt = rest / 5;
    int cout = rt * 16 + (lane & 15);
    int k = ks * 32 + (lane >> 4) * 8 + j;
    float v = 0.f;
    if (k < 128) v = w[cout * 131 + 3 + k];
    else if (k < 131) v = w[cout * 131 + (k - 128)];
    wswz[i] = f2bf(v);
}

// ---------------- K1: shift conv + BN(train) + ReLU, fp64 to match np ref ----------------
__global__ __launch_bounds__(1024) void k_shift(const float* __restrict__ ffps,
                                                const float* __restrict__ wsh,
                                                const float* __restrict__ gam,
                                                const float* __restrict__ bet,
                                                double* __restrict__ nxd,
                                                float* __restrict__ nxf) {
#pragma clang fp contract(off)
    __shared__ double red[6][1024];
    __shared__ double par[6];
    int t = threadIdx.x;
    double w[9];
#pragma unroll
    for (int i = 0; i < 9; i++) w[i] = (double)wsh[i];
    double x[8][3];
    double s[3] = {0, 0, 0}, sq[3] = {0, 0, 0};
#pragma unroll
    for (int i = 0; i < 8; i++) {
        int p = t + 1024 * i;
        double f0 = (double)ffps[p * 3 + 0];
        double f1 = (double)ffps[p * 3 + 1];
        double f2 = (double)ffps[p * 3 + 2];
#pragma unroll
        for (int o = 0; o < 3; o++) {
            double xo = (w[o * 3 + 0] * f0 + w[o * 3 + 1] * f1) + w[o * 3 + 2] * f2;
            x[i][o] = xo;
            s[o] += xo;
            sq[o] += xo * xo;
        }
    }
#pragma unroll
    for (int o = 0; o < 3; o++) { red[o][t] = s[o]; red[3 + o][t] = sq[o]; }
    for (int off = 512; off > 0; off >>= 1) {
        __syncthreads();
        if (t < off) {
#pragma unroll
            for (int j = 0; j < 6; j++) red[j][t] += red[j][t + off];
        }
    }
    __syncthreads();
    if (t == 0) {
#pragma unroll
        for (int o = 0; o < 3; o++) {
            double m = red[o][0] / (double)BP;
            double v = red[3 + o][0] / (double)BP - m * m;
            par[o] = m;
            par[3 + o] = 1.0 / sqrt(v + 1e-5);
        }
    }
    __syncthreads();
    double gv[3] = {(double)gam[0], (double)gam[1], (double)gam[2]};
    double bv[3] = {(double)bet[0], (double)bet[1], (double)bet[2]};
#pragma unroll
    for (int i = 0; i < 8; i++) {
        int p = t + 1024 * i;
#pragma unroll
        for (int o = 0; o < 3; o++) {
            double y = ((x[i][o] - par[o]) * par[3 + o]) * gv[o] + bv[o];
            y = (y > 0.0) ? y : 0.0;
            nxd[p * 3 + o] = y;
            nxf[p * 3 + o] = (float)y;
        }
    }
}

// ---------------- K2: ball query, 4-chunk batched + prefetch pipeline ----------------
// R5 counters: 58.6 us, VALUBusy 5.4%, occ 11% -> serialized per-chunk latency
// (~1100 cyc) x 128-chunk worst-case scans. Loads are iteration-independent, so
// batch 4 chunks/iter and prefetch the next 4 unconditionally (clamped index)
// -> one load-latency amortized over 8 chunks in flight. Semantics identical:
// sub-chunks processed in index order; break granularity only wastes ballots.
__global__ __launch_bounds__(256) void k_ballq(const float* __restrict__ bbxyz,
                                               const double* __restrict__ nxd,
                                               int* __restrict__ idxo) {
#pragma clang fp contract(off)
    int t = threadIdx.x;
    int wv = t >> 6, lane = t & 63;
    int q = blockIdx.x * 4 + wv;                   // bp index
    int b = q >> 11;                               // P = 2048
    double qx = nxd[q * 3 + 0], qy = nxd[q * 3 + 1], qz = nxd[q * 3 + 2];
    const double R2 = 0.8 * 0.8;
    // early-out: ball cannot intersect backbone cube [-1,1]^3 -> zero neighbors,
    // reference pads with index 0 in that case.
    {
        double ex = fmax(fmax(qx - 1.0, -1.0 - qx), 0.0);
        double ey = fmax(fmax(qy - 1.0, -1.0 - qy), 0.0);
        double ez = fmax(fmax(qz - 1.0, -1.0 - qz), 0.0);
        if (ex * ex + ey * ey + ez * ez >= R2) {
            if (lane < NS) idxo[q * NS + lane] = 0;
            return;
        }
    }
    const float* base = bbxyz + (size_t)b * N * 3;
    int found = 0, firstn = -1;

    float px[4], py[4], pz[4];
#pragma unroll
    for (int j = 0; j < 4; j++) {
        int n = j * 64 + lane;
        px[j] = base[n * 3 + 0]; py[j] = base[n * 3 + 1]; pz[j] = base[n * 3 + 2];
    }
    for (int cb = 0; cb < 32; cb++) {
        // prefetch next 4 chunks (clamped -> unconditional, stays hoisted)
        float nx[4], ny[4], nz[4];
        int nb = (cb + 1 < 32) ? (cb + 1) * 256 : 0;
#pragma unroll
        for (int j = 0; j < 4; j++) {
            int n = nb + j * 64 + lane;
            nx[j] = base[n * 3 + 0]; ny[j] = base[n * 3 + 1]; nz[j] = base[n * 3 + 2];
        }
        // process current 4 chunks in index order
#pragma unroll
        for (int j = 0; j < 4; j++) {
            int n = cb * 256 + j * 64 + lane;
            double dx = qx - (double)px[j], dy = qy - (double)py[j], dz = qz - (double)pz[j];
            double d2 = (dx * dx + dy * dy) + dz * dz;
            bool within = d2 < R2;
            unsigned long long mask = __ballot(within);
            if (firstn < 0 && mask != 0ull) firstn = (n - lane) + (__ffsll(mask) - 1);
            if (within) {
                int rank = found + __popcll(mask & ((1ull << lane) - 1ull));
                if (rank < NS) idxo[q * NS + rank] = n;
            }
            found += __popcll(mask);
        }
        if (found >= NS) break;
#pragma unroll
        for (int j = 0; j < 4; j++) { px[j] = nx[j]; py[j] = ny[j]; pz[j] = nz[j]; }
    }
    if (found < NS) {
        int padv = (found == 0) ? 0 : firstn;
        if (lane >= found && lane < NS) idxo[q * NS + lane] = padv;
    }
}

// ---------------- K3: MFMA grouped 1x1 conv, pipelined, register-budgeted ----------
// 512 blocks x 8 groups x 2 bp. A = G (m=samples), B = W^T (n=couts). W fragments
// (wreg[5][4], 80 VGPRs) loaded ONCE and live across all groups; acc[4][4] = 64
// VGPRs; total deliberate ~200 < 256 (launch_bounds(256,2)) -> no spill. Feats
// double-buffered via global_load_lds(16B); each wave stages m-tile mt==w.
// xyz enters as in-register ks=4 A-frag.
__global__ __launch_bounds__(256, 2) void k_mlp_mfma(
        const float* __restrict__ bbxyz,
        const unsigned short* __restrict__ featT,
        const unsigned short* __restrict__ wswz,
        const float* __restrict__ nxf,
        const int* __restrict__ idx,
        float* __restrict__ ymax,
        float* __restrict__ partial) {
    // G[buf][(mt*4+ks)*64 + lane][8]: element (s = mt*16+(lane&15), k' = ks*32+(lane>>4)*8+j)
    __shared__ alignas(16) unsigned short G[2][4 * 4 * 64 * 8];   // 2 x 16384 B
    int t = threadIdx.x, lane = t & 63, w = t >> 6;
    int q = lane >> 4, c16 = lane & 15;
    int blk = blockIdx.x;
    int bpbase = blk * (BPB * GRP);                // 16 bp per block
    const bf16x8* wp = (const bf16x8*)wswz;

    // ---- W fragments resident in registers for the whole kernel ----
    bf16x8 wreg[5][4];
#pragma unroll
    for (int ks = 0; ks < 5; ks++)
#pragma unroll
        for (int nt = 0; nt < 4; nt++)
            wreg[ks][nt] = wp[((w * 4 + nt) * 5 + ks) * 64 + lane];

    int n_cur[4], n_nxt[4];
#pragma unroll
    for (int mt = 0; mt < 4; mt++)
        n_cur[mt] = idx[(bpbase + (mt >> 1)) * NS + (mt & 1) * 16 + c16];
    {   // stage group 0: wave w stages m-tile w
        int bp = bpbase + (w >> 1);
        const unsigned short* row = featT + ((size_t)(bp >> 11) * N + n_cur[w]) * C + q * 8;
#pragma unroll
        for (int ks = 0; ks < 4; ks++)
            GLOBAL_LOAD_LDS16(row + ks * 32, &G[0][(w * 4 + ks) * 512]);
    }

    float smA[4] = {0.f, 0.f, 0.f, 0.f}, sqA[4] = {0.f, 0.f, 0.f, 0.f};

    for (int g = 0; g < GRP; g++) {
        int buf = g & 1;
        int bp0 = bpbase + g * BPB;
        if (g + 1 < GRP) {
#pragma unroll
            for (int mt = 0; mt < 4; mt++)
                n_nxt[mt] = idx[(bp0 + BPB + (mt >> 1)) * NS + (mt & 1) * 16 + c16];
        }
        __syncthreads();   // stage(g) drained; compute(g-1) reads of buf^1 done
        if (g + 1 < GRP) {
            int bp = bp0 + BPB + (w >> 1);
            const unsigned short* row = featT + ((size_t)(bp >> 11) * N + n_nxt[w]) * C + q * 8;
#pragma unroll
            for (int ks = 0; ks < 4; ks++)
                GLOBAL_LOAD_LDS16(row + ks * 32, &G[buf ^ 1][(w * 4 + ks) * 512]);
        }

        // ---- compute(g) on G[buf] ----
        f32x4 acc[4][4];
#pragma unroll
        for (int mt = 0; mt < 4; mt++)
#pragma unroll
            for (int nt = 0; nt < 4; nt++) acc[mt][nt] = (f32x4){0.f, 0.f, 0.f, 0.f};

#pragma unroll
        for (int ks = 0; ks < 4; ks++) {
            bf16x8 ag[4];
#pragma unroll
            for (int mt = 0; mt < 4; mt++)
                ag[mt] = *(const bf16x8*)&G[buf][((mt * 4 + ks) * 64 + lane) * 8];
#pragma unroll
            for (int nt = 0; nt < 4; nt++)
#pragma unroll
                for (int mt = 0; mt < 4; mt++)
                    acc[mt][nt] = __builtin_amdgcn_mfma_f32_16x16x32_bf16(ag[mt], wreg[ks][nt], acc[mt][nt], 0, 0, 0);
        }
        {   // ks = 4: xyz A-frags in registers (q==0: j0..2 = recentered xyz, else 0)
            bf16x8 agx[4];
#pragma unroll
            for (int mt = 0; mt < 4; mt++) {
                int bp = bp0 + (mt >> 1);
                unsigned u01 = 0, u23 = 0;
                if (q == 0) {
                    const float* src = bbxyz + ((size_t)(bp >> 11) * N + n_cur[mt]) * 3;
                    const float* ctr = nxf + bp * 3;
                    u01 = (unsigned)f2bf(src[0] - ctr[0]) | ((unsigned)f2bf(src[1] - ctr[1]) << 16);
                    u23 = (unsigned)f2bf(src[2] - ctr[2]);
                }
                union { int4 i; bf16x8 h; } u;
                u.i = make_int4((int)u01, (int)u23, 0, 0);
                agx[mt] = u.h;
            }
#pragma unroll
            for (int nt = 0; nt < 4; nt++)
#pragma unroll
                for (int mt = 0; mt < 4; mt++)
                    acc[mt][nt] = __builtin_amdgcn_mfma_f32_16x16x32_bf16(agx[mt], wreg[4][nt], acc[mt][nt], 0, 0, 0);
        }

        // ---- epilogue: max over 32 samples (2 m-tiles) per bp; sums accumulate ----
#pragma unroll
        for (int pm = 0; pm < BPB; pm++) {
            int bp = bp0 + pm;
#pragma unroll
            for (int nt = 0; nt < 4; nt++) {
                f32x4 a = acc[2 * pm][nt], c = acc[2 * pm + 1][nt];
                float mx = fmaxf(fmaxf(fmaxf(a[0], a[1]), fmaxf(a[2], a[3])),
                                 fmaxf(fmaxf(c[0], c[1]), fmaxf(c[2], c[3])));
                smA[nt] += ((a[0] + a[1]) + (a[2] + a[3])) + ((c[0] + c[1]) + (c[2] + c[3]));
                sqA[nt] += ((a[0] * a[0] + a[1] * a[1]) + (a[2] * a[2] + a[3] * a[3])) +
                           ((c[0] * c[0] + c[1] * c[1]) + (c[2] * c[2] + c[3] * c[3]));
                mx = fmaxf(mx, __shfl_xor(mx, 16, 64));
                mx = fmaxf(mx, __shfl_xor(mx, 32, 64));
                if (q == 0)
                    ymax[(size_t)bp * COUT + w * 64 + nt * 16 + c16] = mx;
            }
        }
#pragma unroll
        for (int mt = 0; mt < 4; mt++) n_cur[mt] = n_nxt[mt];
    }

    // ---- block-level sum butterfly (once) ----
#pragma unroll
    for (int nt = 0; nt < 4; nt++) {
        float sm = smA[nt], sq = sqA[nt];
        sm += __shfl_xor(sm, 16, 64);
        sm += __shfl_xor(sm, 32, 64);
        sq += __shfl_xor(sq, 16, 64);
        sq += __shfl_xor(sq, 32, 64);
        if (q == 0) {
            int cout = w * 64 + nt * 16 + c16;
            partial[(size_t)blk * 512 + cout] = sm;
            partial[(size_t)blk * 512 + 256 + cout] = sq;
        }
    }
}

// ---------------- K4a: reduce partial (512x512) -> (128x512) ----------------
__global__ __launch_bounds__(256) void k_red(const float* __restrict__ partial,
                                             float* __restrict__ p2) {
    int t = threadIdx.x, j = blockIdx.x;
    const float* row = partial + (size_t)j * 4 * 512;
    float s0 = 0.f, s1 = 0.f;
    for (int r = 0; r < 4; r++) {
        s0 += row[r * 512 + t];
        s1 += row[r * 512 + 256 + t];
    }
    p2[j * 512 + t] = s0;
    p2[j * 512 + 256 + t] = s1;
}

// ---------------- K4b: final stats -> per-channel scale/bias ----------------
__global__ __launch_bounds__(256) void k_stats(const float* __restrict__ p2,
                                               const float* __restrict__ gam,
                                               const float* __restrict__ bet,
                                               float* __restrict__ ab) {
    int c = threadIdx.x;
    double sm = 0.0, sq = 0.0;
    for (int r = 0; r < 128; r++) {
        sm += (double)p2[r * 512 + c];
        sq += (double)p2[r * 512 + 256 + c];
    }
    const double cnt = (double)BP * (double)NS;    // 262144
    double mean = sm / cnt;
    double var = sq / cnt - mean * mean;
    double a = (double)gam[c] / sqrt(var + 1e-5);  // gamma==1 -> a>0 always
    double bb = (double)bet[c] - mean * a;
    ab[c] = (float)a;
    ab[256 + c] = (float)bb;
}

// ---------------- K5: out = relu(a * ymax + b)  (a>0 for all channels) ----------------
__global__ __launch_bounds__(256) void k_final(const float* __restrict__ ymax,
                                               const float* __restrict__ ab,
                                               float* __restrict__ out) {
    int e = blockIdx.x * 256 + threadIdx.x;
    int c = e & 255;
    out[e] = fmaxf(ab[c] * ymax[e] + ab[256 + c], 0.f);
}

extern "C" void kernel_launch(void* const* d_in, const int* in_sizes, int n_in,
                              void* d_out, int out_size, void* d_ws, size_t ws_size,
                              hipStream_t stream) {
    const float* ffps  = (const float*)d_in[0];
    const float* bbxyz = (const float*)d_in[1];
    const float* feat  = (const float*)d_in[2];
    const float* wsh   = (const float*)d_in[3];
    const float* gsh   = (const float*)d_in[4];
    const float* bsh   = (const float*)d_in[5];
    const float* wml   = (const float*)d_in[6];
    const float* gml   = (const float*)d_in[7];
    const float* bml   = (const float*)d_in[8];
    float* out = (float*)d_out;
    char* ws = (char*)d_ws;
    if (ws_size < WS_NEED) return;

    unsigned short* featT = (unsigned short*)(ws + OFF_FEATT);
    unsigned short* wswz  = (unsigned short*)(ws + OFF_WSWZ);
    double*         nxd   = (double*)(ws + OFF_NXD);
    float*          nxf   = (float*)(ws + OFF_NXF);
    int*            idx   = (int*)(ws + OFF_IDX);
    float*          ymax  = (float*)(ws + OFF_YMAX);
    float*          part  = (float*)(ws + OFF_PART);
    float*          p2    = (float*)(ws + OFF_P2);
    float*          ab    = (float*)(ws + OFF_AB);

    k_transpose<<<dim3(N / 32, C / 64, B), dim3(32, 8, 1), 0, stream>>>(feat, featT);
    k_wswz<<<dim3(160), dim3(256), 0, stream>>>(wml, wswz);
    k_shift<<<dim3(1), dim3(1024), 0, stream>>>(ffps, wsh, gsh, bsh, nxd, nxf);
    k_ballq<<<dim3(BP / 4), dim3(256), 0, stream>>>(bbxyz, nxd, idx);
    k_mlp_mfma<<<dim3(NBLK), dim3(256), 0, stream>>>(bbxyz, featT, wswz, nxf, idx, ymax, part);
    k_red<<<dim3(128), dim3(256), 0, stream>>>(part, p2);
    k_stats<<<dim3(1), dim3(256), 0, stream>>>(p2, gml, bml, ab);
    k_final<<<dim3(BP * COUT / 256), dim3(256), 0, stream>>>(ymax, ab, out);
}